// Round 8
// baseline (77.814 us; speedup 1.0000x reference)
//
#include <hip/hip_runtime.h>

// B=131072 points (D=16 fp32), K=256 centers. Out (fp32): [B] argmin idx ++ [B,16] offsets.
//
// Round-8: SGPR-PAIR center table + 4 pts/lane.
// Evidence (r2/r5/r7): kernel ~18-25us invariant to occupancy and pk_fma ->
// suspect VALU bloat: v_pk_fma_f32 needs a 64-bit operand, so broadcasting one
// scalar c into (v2f){c,c} costs 2 v_mov per element per center (32 movs vs 16
// pk_fmas). Fix: prep writes rows of DUPLICATED pairs
//   row[k] = {c2,c2}, {-2c_0,-2c_0}, ..., {-2c_15,-2c_15}   (34 floats, 136 B)
// A wave-uniform v2f load of a pair -> aligned SGPR pair -> legal direct
// scalar operand of v_pk_fma_f32 (one scalar read). Zero splats.
// 4 pts/lane = 2 independent v2f accumulator chains (covers 4-cyc FMA latency)
// ~ (2 mov + 32 pk_fma + 12 sel)/4 pts = ~12 VALU ops/pt/center.
//
// score = c2[k] + sum_d x_d * (-2 c_d)  (exactly one -2, in the table; y holds
// RAW x — round-6 double-scale bug guarded). Same per-point op order as r7
// (absmax 0). Strict < + ascending k/chunk => lowest-k ties like jnp.argmin.
//
// Block = 512 thr = 8 waves, 256 points (lane l owns pts base+{0,64,128,192});
// wave w scans centers [32w, 32w+32). Grid 512 blocks = 2/CU resident.

constexpr int Bn = 131072;
constexpr int Kn = 256;
constexpr int Dn = 16;
constexpr int PPL = 4;             // points per lane
constexpr int PTS = PPL * 64;      // 256 points per block
constexpr int NW = 8;              // waves per block == K chunks
constexpr int KC = Kn / NW;        // 32 centers per wave
constexpr int ROW = 2 + 2 * Dn;    // 34 floats per table row

typedef float v2f __attribute__((ext_vector_type(2)));

__global__ __launch_bounds__(64) void prep_kernel(
    const float* __restrict__ centers, float* __restrict__ tab) {
  int t = blockIdx.x * 64 + threadIdx.x;
  if (t < Kn) {
    const float* c = centers + t * Dn;
    float2 buf[17];
    float s = 0.0f;
#pragma unroll
    for (int d = 0; d < Dn; ++d) {
      float cd = c[d];
      s = fmaf(cd, cd, s);
      buf[1 + d] = make_float2(-2.0f * cd, -2.0f * cd);
    }
    buf[0] = make_float2(s, s);
    float2* r = reinterpret_cast<float2*>(tab + (size_t)t * ROW);
#pragma unroll
    for (int j = 0; j < 17; ++j) r[j] = buf[j];
  }
}

__global__ __launch_bounds__(512, 4) void kmeans_kernel(
    const float* __restrict__ traj, const float* __restrict__ centers,
    const float* __restrict__ tab, float* __restrict__ out) {
  __shared__ float sbest[NW * PTS];
  __shared__ int sbi[NW * PTS];
  __shared__ int swin[PTS];

  const int t = threadIdx.x;
  const int blk = blockIdx.x;
  const int w = __builtin_amdgcn_readfirstlane(t >> 6);  // wave id (SGPR)
  const int l = t & 63;                                  // lane
  const int pbase = blk * PTS + l;   // lane's points: pbase + {0,64,128,192}

  // ---- RAW x, packed: y0[d]={x_p0,x_p1}, y1[d]={x_p2,x_p3}.
  v2f y0[Dn], y1[Dn];
  {
    const float4* xa = reinterpret_cast<const float4*>(traj + (size_t)(pbase      ) * Dn);
    const float4* xb = reinterpret_cast<const float4*>(traj + (size_t)(pbase +  64) * Dn);
    const float4* xc = reinterpret_cast<const float4*>(traj + (size_t)(pbase + 128) * Dn);
    const float4* xd = reinterpret_cast<const float4*>(traj + (size_t)(pbase + 192) * Dn);
#pragma unroll
    for (int q = 0; q < 4; ++q) {
      float4 a = xa[q], b = xb[q], c = xc[q], d = xd[q];
      y0[q * 4 + 0] = (v2f){a.x, b.x};  y1[q * 4 + 0] = (v2f){c.x, d.x};
      y0[q * 4 + 1] = (v2f){a.y, b.y};  y1[q * 4 + 1] = (v2f){c.y, d.y};
      y0[q * 4 + 2] = (v2f){a.z, b.z};  y1[q * 4 + 2] = (v2f){c.z, d.z};
      y0[q * 4 + 3] = (v2f){a.w, b.w};  y1[q * 4 + 3] = (v2f){c.w, d.w};
    }
  }

  // ---- k-loop: wave-uniform rows of v2f pairs -> s_load -> SGPR-pair pk_fma.
  float best0 = __builtin_inff(), best1 = __builtin_inff();
  float best2 = __builtin_inff(), best3 = __builtin_inff();
  int bi0 = 0, bi1 = 0, bi2 = 0, bi3 = 0;
  const int k0 = w * KC;
#pragma unroll 2
  for (int kk = 0; kk < KC; ++kk) {
    const int k = k0 + kk;
    const v2f* row = reinterpret_cast<const v2f*>(tab + (size_t)k * ROW);
    v2f a0 = row[0];                 // {c2,c2} -> acc init
    v2f a1 = a0;
#pragma unroll
    for (int d = 0; d < Dn; ++d) {
      const v2f c = row[1 + d];      // aligned SGPR pair, no splat
      a0 = y0[d] * c + a0;           // v_pk_fma_f32 with scalar-pair operand
      a1 = y1[d] * c + a1;
    }
    if (a0.x < best0) { best0 = a0.x; bi0 = k; }
    if (a0.y < best1) { best1 = a0.y; bi1 = k; }
    if (a1.x < best2) { best2 = a1.x; bi2 = k; }
    if (a1.y < best3) { best3 = a1.y; bi3 = k; }
  }
  sbest[w * PTS + l      ] = best0;  sbi[w * PTS + l      ] = bi0;
  sbest[w * PTS + l +  64] = best1;  sbi[w * PTS + l +  64] = bi1;
  sbest[w * PTS + l + 128] = best2;  sbi[w * PTS + l + 128] = bi2;
  sbest[w * PTS + l + 192] = best3;  sbi[w * PTS + l + 192] = bi3;
  __syncthreads();

  // ---- Cross-wave reduction: threads 0..255, one per point; ascending chunk
  // order + strict < keeps the lowest-k winner on exact ties.
  if (t < PTS) {
    float b0 = sbest[t];
    int i0 = sbi[t];
#pragma unroll
    for (int ww = 1; ww < NW; ++ww) {
      float b1 = sbest[ww * PTS + t];
      int i1 = sbi[ww * PTS + t];
      if (b1 < b0) { b0 = b1; i0 = i1; }
    }
    swin[t] = i0;
    out[blk * PTS + t] = (float)i0;  // idx output (fp32 buffer), coalesced
  }
  __syncthreads();

  // ---- Coalesced offset stores: 256 pts x 4 quarters = 1024 float4 ops.
#pragma unroll
  for (int it = 0; it < 2; ++it) {
    const int id = it * 512 + t;
    const int pb = id >> 2, q = id & 3;
    const int pt = blk * PTS + pb;
    const int win = swin[pb];
    float4 xv = reinterpret_cast<const float4*>(traj + (size_t)pt * Dn)[q];  // L1-hot
    float4 cv = reinterpret_cast<const float4*>(centers + (size_t)win * Dn)[q];
    float4 o = make_float4(xv.x - cv.x, xv.y - cv.y, xv.z - cv.z, xv.w - cv.w);
    reinterpret_cast<float4*>(out + Bn)[(size_t)pt * 4 + q] = o;
  }
}

extern "C" void kernel_launch(void* const* d_in, const int* in_sizes, int n_in,
                              void* d_out, int out_size, void* d_ws, size_t ws_size,
                              hipStream_t stream) {
  (void)in_sizes; (void)n_in; (void)out_size; (void)ws_size;
  const float* traj = (const float*)d_in[0];     // [131072, 16]
  const float* centers = (const float*)d_in[1];  // [256, 16]
  float* out = (float*)d_out;                    // [131072] idx ++ [131072*16] offsets

  float* tab = (float*)d_ws;                     // 256 rows x 34 floats = 34 KB

  prep_kernel<<<4, 64, 0, stream>>>(centers, tab);
  kmeans_kernel<<<Bn / PTS, 512, 0, stream>>>(traj, centers, tab, out);
}

// Round 11
// 73.361 us; speedup vs baseline: 1.0607x; 1.0607x over previous
//
#include <hip/hip_runtime.h>

// B=131072 points (D=16 fp32), K=256 centers. Out (fp32): [B] argmin idx ++ [B,16] offsets.
//
// Round-11: LDS-gather epilogue. Evidence r2-r8: kernel ~19-25us invariant to
// k-loop formulation & occupancy -> the dominant cost must be COMMON to all:
// the stage-3b centers[win] gather (win data-random per lane => each
// global_load_dwordx4 touches up to 64 cache lines, serialized in L1/TA;
// ~8192 wave-gathers x ~500cyc ~ 7us, present unchanged in every round).
// Fix: stage centers into LDS in stage-1 (same regs already loaded for c2),
// gather the winner's quarters via ds_read_b128 (random-row LDS gather ~0.3us
// total). k-loop and all other structure byte-identical to round 5 (74.2us).
//
// Structure (r5): block = 256 thr = 4 waves, 128 points (2/lane packed in
// v2f; y*c+acc contracts to v_pk_fma_f32). Wave w scans centers [64w,64w+64);
// k wave-uniform -> s_load broadcast. score = c2[k] - 2*x.c (x2 per-point
// const, argmin-invariant; strict < + ascending k => lowest-k ties, matching
// jnp.argmin). absmax 0 expected (identical arithmetic to r5/r7).

constexpr int Bn = 131072;
constexpr int Kn = 256;
constexpr int Dn = 16;
constexpr int PTS = 128;      // points per block (2 per lane)
constexpr int NW = 4;         // waves per block == K chunks
constexpr int KC = Kn / NW;   // 64 centers per wave

typedef float v2f __attribute__((ext_vector_type(2)));

__global__ __launch_bounds__(256, 7) void kmeans_kernel(
    const float* __restrict__ traj, const float* __restrict__ centers,
    float* __restrict__ out) {
  __shared__ float c2s[Kn];
  __shared__ float4 cs4[Kn][4];     // centers copy for the epilogue gather (16KB)
  __shared__ float sbest[NW * PTS];
  __shared__ int sbi[NW * PTS];
  __shared__ int swin[PTS];

  const int t = threadIdx.x;
  const int blk = blockIdx.x;

  // ---- Stage 1: thread t loads center row t (4x float4), computes c2, and
  // stages the row into LDS for the epilogue gather.
  {
    const float4* cp = reinterpret_cast<const float4*>(centers + t * Dn);
    float4 a = cp[0], b = cp[1], c = cp[2], d = cp[3];
    float s = 0.0f;
    s = fmaf(a.x, a.x, s); s = fmaf(a.y, a.y, s);
    s = fmaf(a.z, a.z, s); s = fmaf(a.w, a.w, s);
    s = fmaf(b.x, b.x, s); s = fmaf(b.y, b.y, s);
    s = fmaf(b.z, b.z, s); s = fmaf(b.w, b.w, s);
    s = fmaf(c.x, c.x, s); s = fmaf(c.y, c.y, s);
    s = fmaf(c.z, c.z, s); s = fmaf(c.w, c.w, s);
    s = fmaf(d.x, d.x, s); s = fmaf(d.y, d.y, s);
    s = fmaf(d.z, d.z, s); s = fmaf(d.w, d.w, s);
    c2s[t] = s;
    cs4[t][0] = a; cs4[t][1] = b; cs4[t][2] = c; cs4[t][3] = d;
  }
  __syncthreads();

  const int w = __builtin_amdgcn_readfirstlane(t >> 6);  // wave id (SGPR)
  const int l = t & 63;                                  // lane
  const int p0 = blk * PTS + l;        // this lane's point 0
  const int p1 = p0 + 64;              // this lane's point 1

  // ---- Load y = -2*x for both points, packed {pt0, pt1} per dim.
  v2f y[Dn];
  {
    const float4* xa = reinterpret_cast<const float4*>(traj + (size_t)p0 * Dn);
    const float4* xb = reinterpret_cast<const float4*>(traj + (size_t)p1 * Dn);
#pragma unroll
    for (int q = 0; q < 4; ++q) {
      float4 a = xa[q], b = xb[q];
      y[q * 4 + 0] = (v2f){-2.0f * a.x, -2.0f * b.x};
      y[q * 4 + 1] = (v2f){-2.0f * a.y, -2.0f * b.y};
      y[q * 4 + 2] = (v2f){-2.0f * a.z, -2.0f * b.z};
      y[q * 4 + 3] = (v2f){-2.0f * a.w, -2.0f * b.w};
    }
  }

  float best0 = __builtin_inff(), best1 = __builtin_inff();
  int bi0 = 0, bi1 = 0;
  const int k0 = w * KC;
#pragma unroll 4
  for (int kk = 0; kk < KC; ++kk) {
    const int k = k0 + kk;
    const float* cr = centers + k * Dn;  // wave-uniform -> s_load
    const float c2k = c2s[k];
    v2f acc = (v2f){c2k, c2k};
#pragma unroll
    for (int d = 0; d < Dn; ++d) {
      const float c = cr[d];             // SGPR; broadcast into both halves
      acc = y[d] * (v2f){c, c} + acc;    // contracts to v_pk_fma_f32
    }
    if (acc.x < best0) { best0 = acc.x; bi0 = k; }  // strict <: lowest-k ties
    if (acc.y < best1) { best1 = acc.y; bi1 = k; }
  }
  sbest[w * PTS + l] = best0;
  sbi[w * PTS + l] = bi0;
  sbest[w * PTS + 64 + l] = best1;
  sbi[w * PTS + 64 + l] = bi1;
  __syncthreads();

  // ---- Cross-wave reduction: threads 0..127, one per point. Ascending chunk
  // order + strict < keeps the lowest-k winner on exact ties.
  if (t < PTS) {
    float b0 = sbest[t];
    int i0 = sbi[t];
#pragma unroll
    for (int ww = 1; ww < NW; ++ww) {
      float b1 = sbest[ww * PTS + t];
      int i1 = sbi[ww * PTS + t];
      if (b1 < b0) { b0 = b1; i0 = i1; }
    }
    swin[t] = i0;
    out[blk * PTS + t] = (float)i0;  // idx output (fp32 buffer), coalesced
  }
  __syncthreads();

  // ---- Coalesced offset stores: 128 points x 4 quarters = 512 float4 ops.
  // x re-read from traj is coalesced + L1-hot; center quarter now comes from
  // the LDS copy (ds_read_b128 random-row gather) instead of the divergent
  // global gather — the round-11 change.
#pragma unroll
  for (int it = 0; it < 2; ++it) {
    const int id = it * 256 + t;
    const int pb = id >> 2, q = id & 3;
    const int pt = blk * PTS + pb;
    const int win = swin[pb];
    float4 xv = reinterpret_cast<const float4*>(traj + (size_t)pt * Dn)[q];  // L1-hot
    float4 cv = cs4[win][q];                                                 // LDS gather
    float4 o = make_float4(xv.x - cv.x, xv.y - cv.y, xv.z - cv.z, xv.w - cv.w);
    reinterpret_cast<float4*>(out + Bn)[(size_t)pt * 4 + q] = o;
  }
}

extern "C" void kernel_launch(void* const* d_in, const int* in_sizes, int n_in,
                              void* d_out, int out_size, void* d_ws, size_t ws_size,
                              hipStream_t stream) {
  (void)in_sizes; (void)n_in; (void)out_size; (void)d_ws; (void)ws_size;
  const float* traj = (const float*)d_in[0];     // [131072, 16]
  const float* centers = (const float*)d_in[1];  // [256, 16]
  float* out = (float*)d_out;                    // [131072] idx ++ [131072*16] offsets
  kmeans_kernel<<<Bn / PTS, 256, 0, stream>>>(traj, centers, out);
}